// Round 11
// baseline (10437.816 us; speedup 1.0000x reference)
//
#include <hip/hip_runtime.h>
#include <stdint.h>

#define NBATCH 16
#define NPTS   131072
#define NPOINT 4096
#define KWG    16                    // workgroups per batch
#define TPB    512
#define NWAVE  (TPB/64)              // 8
#define PPT    (NPTS/(KWG*TPB))      // 16 points per thread
#define SEG    (NPTS/KWG)            // 8192
#define SEGSH  13                    // log2(SEG)

typedef unsigned long long u64;
typedef unsigned int u32;

#define LDA(p)    __hip_atomic_load((p),  __ATOMIC_RELAXED, __HIP_MEMORY_SCOPE_AGENT)
#define STA(p,v)  __hip_atomic_store((p),(v),__ATOMIC_RELAXED,__HIP_MEMORY_SCOPE_AGENT)
#define LDW(p)    __hip_atomic_load((p),  __ATOMIC_RELAXED, __HIP_MEMORY_SCOPE_WORKGROUP)
#define LDWA(p)   __hip_atomic_load((p),  __ATOMIC_ACQUIRE, __HIP_MEMORY_SCOPE_WORKGROUP)
#define STW(p,v)  __hip_atomic_store((p),(v),__ATOMIC_RELAXED,__HIP_MEMORY_SCOPE_WORKGROUP)
#define STWR(p,v) __hip_atomic_store((p),(v),__ATOMIC_RELEASE,__HIP_MEMORY_SCOPE_WORKGROUP)

// ---- DPP helpers (R8-proven) ----
template<int CTRL>
__device__ __forceinline__ u32 dpp32(u32 x) {
    return (u32)__builtin_amdgcn_update_dpp(0, (int)x, CTRL, 0xf, 0xf, true);
}
__device__ __forceinline__ u32 umax_(u32 a, u32 b) { return a > b ? a : b; }
__device__ __forceinline__ u32 wave_umax(u32 x) {
    x = umax_(x, dpp32<0xB1>(x));
    x = umax_(x, dpp32<0x4E>(x));
    x = umax_(x, dpp32<0x124>(x));
    x = umax_(x, dpp32<0x128>(x));
    x = umax_(x, (u32)__builtin_amdgcn_ds_swizzle((int)x, 0x401F));
    x = umax_(x, (u32)__shfl_xor((int)x, 32, 64));
    return x;
}
template<int CTRL>
__device__ __forceinline__ u64 dpp64max(u64 x) {
    u32 lo = dpp32<CTRL>((u32)x);
    u32 hi = dpp32<CTRL>((u32)(x >> 32));
    u64 o = ((u64)hi << 32) | lo;
    return o > x ? o : x;
}
__device__ __forceinline__ u64 row16_umax64(u64 k) {
    k = dpp64max<0xB1>(k);
    k = dpp64max<0x4E>(k);
    k = dpp64max<0x124>(k);
    k = dpp64max<0x128>(k);
    return k;
}
__device__ __forceinline__ u64 shfl_u64(u64 v, int s) {
    u32 lo = (u32)__shfl((int)(u32)v, s, 64);
    u32 hi = (u32)__shfl((int)(u32)(v >> 32), s, 64);
    return ((u64)hi << 32) | lo;
}

// compile-time select from 16 unrolled regs (rule #20; wave-uniform k)
#define SEL16(arr,k,out_) do { \
    float a0=((k)&1)?arr[1]:arr[0];  float a1=((k)&1)?arr[3]:arr[2];   \
    float a2=((k)&1)?arr[5]:arr[4];  float a3=((k)&1)?arr[7]:arr[6];   \
    float a4=((k)&1)?arr[9]:arr[8];  float a5=((k)&1)?arr[11]:arr[10]; \
    float a6=((k)&1)?arr[13]:arr[12];float a7=((k)&1)?arr[15]:arr[14]; \
    float b0_=((k)&2)?a1:a0; float b1_=((k)&2)?a3:a2; \
    float b2_=((k)&2)?a5:a4; float b3_=((k)&2)?a7:a6; \
    float c0_=((k)&4)?b1_:b0_; float c1_=((k)&4)?b3_:b2_; \
    out_=((k)&8)?c1_:c0_; } while(0)

// Global slot = 4 self-tagged u64 (32B, peer-contiguous):
//   w0=[tag:15][dist:32][inv:17]  w1..w3=[tag:15][coord_f32:32][0:17]
// ring: [batch][parity][16 peers][4 words]. Depth-2 parity safety: WG A
// overwrites (p) at t+2 only after A wrote bc(t+1) <= A detected all peers'
// (t+1) words <= every peer finished t. Poison tag 21845>4095 never matches;
// replay-stale values equal fresh ones (deterministic trajectory).
// LDS handshakes (no __syncthreads in the round loop):
//   s1[wave][4]: per-wave tagged {key,x,y,z}; wave0 spins on tags.
//   sbc[3]: tagged winner {x,y,z} words; waves 1-7 spin on sbc[2] (release).
__global__ __launch_bounds__(TPB, 2) void fps_kernel(
    const float* __restrict__ xyz, const int* __restrict__ finit,
    int* __restrict__ out, u64* __restrict__ ring)
{
    const int b    = blockIdx.x >> 4;
    const int w    = blockIdx.x & 15;
    const int tid  = threadIdx.x;
    const int lane = tid & 63;
    const int wv   = tid >> 6;

    const float* xb = xyz + (size_t)b * NPTS * 3;
    const int base = w * SEG;

    // register-resident point state
    float px[PPT], py[PPT], pz[PPT], pd[PPT];
    u32 inv[PPT];
    #pragma unroll
    for (int j = 0; j < PPT; ++j) {
        int idx = base + j * TPB + tid;          // coalesced initial load
        px[j] = xb[(size_t)idx * 3 + 0];
        py[j] = xb[(size_t)idx * 3 + 1];
        pz[j] = xb[(size_t)idx * 3 + 2];
        pd[j] = 1e10f;
        inv[j] = (u32)(NPTS - 1 - idx);
    }

    __shared__ u64 s1[NWAVE * 4];
    __shared__ u64 sbc[3];

    const int f0 = finit[b];
    if (w == 0 && tid == 0) out[b * NPOINT] = f0;
    float cx = xb[(size_t)f0 * 3 + 0];
    float cy = xb[(size_t)f0 * 3 + 1];
    float cz = xb[(size_t)f0 * 3 + 2];

    u64* bring = ring + (size_t)b * 2 * KWG * 4;  // [2][16][4]

    for (int t = 1; t < NPOINT; ++t) {
        // ---- pass1: distance update (golden fp32 form) + 4-way max trees ----
        float m0 = -1.0f, m1 = -1.0f, m2 = -1.0f, m3 = -1.0f;
        #pragma unroll
        for (int j = 0; j < PPT; ++j) {
            float dx = __fsub_rn(px[j], cx);
            float dy = __fsub_rn(py[j], cy);
            float dz = __fsub_rn(pz[j], cz);
            float d  = __fmaf_rn(dz, dz, __fmaf_rn(dy, dy, __fmul_rn(dx, dx)));
            float nd = fminf(pd[j], d);
            pd[j] = nd;
            if ((j & 3) == 0)      m0 = fmaxf(m0, nd);
            else if ((j & 3) == 1) m1 = fmaxf(m1, nd);
            else if ((j & 3) == 2) m2 = fmaxf(m2, nd);
            else                   m3 = fmaxf(m3, nd);
        }
        float mx = fmaxf(fmaxf(m0, m1), fmaxf(m2, m3));
        u32 mxb = wave_umax(__float_as_uint(mx));        // wave max
        // ---- pass2: max inv among wave-level ties ----
        u32 b0 = 0, b1 = 0, b2 = 0, b3 = 0;
        #pragma unroll
        for (int j = 0; j < PPT; ++j) {
            bool tie = (__float_as_uint(pd[j]) == mxb);
            if ((j & 3) == 0)      b0 = tie ? umax_(b0, inv[j]) : b0;
            else if ((j & 3) == 1) b1 = tie ? umax_(b1, inv[j]) : b1;
            else if ((j & 3) == 2) b2 = tie ? umax_(b2, inv[j]) : b2;
            else                   b3 = tie ? umax_(b3, inv[j]) : b3;
        }
        u32 bv = wave_umax(umax_(umax_(b0, b1), umax_(b2, b3)));

        const u64 tt  = (u64)(u32)t;
        const u64 tg  = tt << 49;
        // ---- wave-winner coords from registers (SEL16 + shuffles) ----
        int local    = ((NPTS - 1) - (int)bv) - base;    // j*TPB + tid
        int jwin     = local >> 9;                       // TPB=512
        int lane_win = local & 63;                       // winner is in this wave
        float sx, sy, sz;
        SEL16(px, jwin, sx); SEL16(py, jwin, sy); SEL16(pz, jwin, sz);
        sx = __shfl(sx, lane_win, 64);
        sy = __shfl(sy, lane_win, 64);
        sz = __shfl(sz, lane_win, 64);
        // ---- stage-1 post: 4 tagged LDS words per wave (no barrier) ----
        u64 sval = (lane == 0) ? (tg | ((u64)mxb << 17) | (u64)bv)
                 : (lane == 1) ? (tg | ((u64)__float_as_uint(sx) << 17))
                 : (lane == 2) ? (tg | ((u64)__float_as_uint(sy) << 17))
                 :               (tg | ((u64)__float_as_uint(sz) << 17));
        if (lane < 4) STW(&s1[(wv << 2) | lane], sval);

        if (wv == 0) {
            // ---- gather 8 waves x 4 words: lane<32, wave=(l&7), word=(l>>3) ----
            u64 g1 = 0;
            if (lane < 32) {
                u64* a = &s1[((lane & 7) << 2) | (lane >> 3)];
                do { g1 = LDW(a); } while ((g1 >> 49) != tt);
            }
            // block key = max over key-words (lanes 0-7; 8-15 zeroed)
            u64 kred = (lane < 8) ? g1 : 0;
            kred = row16_umax64(kred);
            u64 kb = shfl_u64(kred, 0);                  // broadcast to all 64
            int bidx = (NPTS - 1) - (int)(kb & 0x1FFFF);
            int Wst  = ((bidx - base) >> 6) & (NWAVE - 1);  // winner wave
            u64 vX = shfl_u64(g1, 8 + Wst);
            u64 vY = shfl_u64(g1, 16 + Wst);
            u64 vZ = shfl_u64(g1, 24 + Wst);
            // ---- publish 4 global words (lanes 0-3, one store instr) ----
            u64* bpp = bring + ((size_t)(t & 1) << 6);   // [parity][16][4]
            u64 pval = (lane == 0) ? kb : (lane == 1) ? vX : (lane == 2) ? vY : vZ;
            if (lane < 4) STA(&bpp[(w << 2) | lane], pval);
            // ---- poll: all 64 lanes, peer=(l&15), word=(l>>4); self local ----
            const int peer = lane & 15, word = lane >> 4;
            u64 g = (word == 0) ? kb : (word == 1) ? vX : (word == 2) ? vY : vZ;
            if (peer != w) {
                u64* sp = &bpp[(peer << 2) | word];
                u64 ga = LDA(sp);
                for (;;) {                               // 2-deep pipelined (R8)
                    u64 gb = LDA(sp);
                    if ((ga >> 49) == tt) { g = ga; break; }
                    ga = LDA(sp);
                    if ((gb >> 49) == tt) { g = gb; break; }
                }
            }
            // ---- winner over 16 peers (key-words on lanes 0-15) ----
            u64 K2 = row16_umax64((lane < 16) ? g : 0);
            u64 K0 = shfl_u64(K2, 0);
            int bi   = (NPTS - 1) - (int)(K0 & 0x1FFFF);
            int Pst  = bi >> SEGSH;                      // winner WG
            u64 gx = shfl_u64(g, 16 + Pst);
            u64 gy = shfl_u64(g, 32 + Pst);
            u64 gz = shfl_u64(g, 48 + Pst);
            // ---- broadcast centroid via tagged LDS (release on last) ----
            if (lane == 0) {
                STW(&sbc[0], gx);
                STW(&sbc[1], gy);
                STWR(&sbc[2], gz);
                if (w == 0) out[b * NPOINT + t] = bi;
            }
            cx = __uint_as_float((u32)(gx >> 17));
            cy = __uint_as_float((u32)(gy >> 17));
            cz = __uint_as_float((u32)(gz >> 17));
        } else {
            // ---- waves 1-7: spin on tagged centroid ----
            u64 gz;
            do { gz = LDWA(&sbc[2]); } while ((gz >> 49) != tt);
            u64 gx = LDW(&sbc[0]);
            u64 gy = LDW(&sbc[1]);
            cx = __uint_as_float((u32)(gx >> 17));
            cy = __uint_as_float((u32)(gy >> 17));
            cz = __uint_as_float((u32)(gz >> 17));
        }
    }
}

extern "C" void kernel_launch(void* const* d_in, const int* in_sizes, int n_in,
                              void* d_out, int out_size, void* d_ws, size_t ws_size,
                              hipStream_t stream) {
    const float* xyz   = (const float*)d_in[0];
    const int*   finit = (const int*)d_in[1];
    int*         out   = (int*)d_out;
    u64*         ring  = (u64*)d_ws;   // 16*2*16*4*8 = 16 KiB; tag-checked, no init

    void* args[] = { (void*)&xyz, (void*)&finit, (void*)&out, (void*)&ring };
    dim3 grid(NBATCH * KWG), block(TPB);
    if (hipLaunchCooperativeKernel((const void*)fps_kernel, grid, block, args, 0, stream)
        != hipSuccess) {
        // 256 blocks x 8 waves, 1 WG/CU -> co-resident anyway
        fps_kernel<<<grid, block, 0, stream>>>(xyz, finit, out, ring);
    }
}

// Round 12
// 9574.008 us; speedup vs baseline: 1.0902x; 1.0902x over previous
//
#include <hip/hip_runtime.h>
#include <stdint.h>

#define NBATCH 16
#define NPTS   131072
#define NPOINT 4096
#define KWG    16                    // workgroups per batch
#define TPB    512
#define NWAVE  (TPB/64)              // 8
#define PPT    (NPTS/(KWG*TPB))      // 16 points per thread
#define SEG    (NPTS/KWG)            // 8192
#define SEGSH  13                    // log2(SEG)

typedef unsigned long long u64;
typedef unsigned int u32;

// ---- DPP helpers (R8-proven) ----
template<int CTRL>
__device__ __forceinline__ u32 dpp32(u32 x) {
    return (u32)__builtin_amdgcn_update_dpp(0, (int)x, CTRL, 0xf, 0xf, true);
}
__device__ __forceinline__ u32 umax_(u32 a, u32 b) { return a > b ? a : b; }

__device__ __forceinline__ u32 wave_umax(u32 x) {
    x = umax_(x, dpp32<0xB1>(x));    // quad_perm xor1
    x = umax_(x, dpp32<0x4E>(x));    // quad_perm xor2
    x = umax_(x, dpp32<0x124>(x));   // row_ror:4
    x = umax_(x, dpp32<0x128>(x));   // row_ror:8 -> row16 all-reduced
    x = umax_(x, (u32)__builtin_amdgcn_ds_swizzle((int)x, 0x401F)); // xor16
    x = umax_(x, (u32)__shfl_xor((int)x, 32, 64));                  // xor32
    return x;
}
template<int CTRL>
__device__ __forceinline__ u64 dpp64max(u64 x) {
    u32 lo = dpp32<CTRL>((u32)x);
    u32 hi = dpp32<CTRL>((u32)(x >> 32));
    u64 o = ((u64)hi << 32) | lo;
    return o > x ? o : x;
}
__device__ __forceinline__ u64 row16_umax64(u64 k) {
    k = dpp64max<0xB1>(k);
    k = dpp64max<0x4E>(k);
    k = dpp64max<0x124>(k);
    k = dpp64max<0x128>(k);
    return k;
}
__device__ __forceinline__ u64 shfl_u64(u64 v, int s) {
    u32 lo = (u32)__shfl((int)(u32)v, s, 64);
    u32 hi = (u32)__shfl((int)(u32)(v >> 32), s, 64);
    return ((u64)hi << 32) | lo;
}

// compile-time select from 16 unrolled regs (rule #20; k wave-uniform)
#define SEL16(arr,k,out_) do { \
    float a0=((k)&1)?arr[1]:arr[0];  float a1=((k)&1)?arr[3]:arr[2];   \
    float a2=((k)&1)?arr[5]:arr[4];  float a3=((k)&1)?arr[7]:arr[6];   \
    float a4=((k)&1)?arr[9]:arr[8];  float a5=((k)&1)?arr[11]:arr[10]; \
    float a6=((k)&1)?arr[13]:arr[12];float a7=((k)&1)?arr[15]:arr[14]; \
    float b0_=((k)&2)?a1:a0; float b1_=((k)&2)?a3:a2; \
    float b2_=((k)&2)?a5:a4; float b3_=((k)&2)?a7:a6; \
    float c0_=((k)&4)?b1_:b0_; float c1_=((k)&4)?b3_:b2_; \
    out_=((k)&8)?c1_:c0_; } while(0)

// slot words (word-major): region[word][peer], word 0=key 1=x 2=y 3=z.
//   w0=[tag:15][dist_f32_bits:32][inv:17]  w1..3=[tag:15][coord_f32:32][0:17]
// Keys region = one 128B line -> key poll footprint unchanged vs R8.
// ring: [batch][parity][4 words][16 peers]. Depth-2 parity ring safety as
// R4-R11: producer reuses parity p at t+2 only after barrier(t+1) <= all
// peers consumed t. Poison tag (0xAA.. -> 21845) never matches a round tag;
// replay-stale values are deterministic-identical -> benign.
__global__ __launch_bounds__(TPB, 2) void fps_kernel(
    const float* __restrict__ xyz, const int* __restrict__ finit,
    int* __restrict__ out, u64* __restrict__ ring)
{
    const int b    = blockIdx.x >> 4;
    const int w    = blockIdx.x & 15;
    const int tid  = threadIdx.x;
    const int lane = tid & 63;
    const int wv   = tid >> 6;

    const float* xb = xyz + (size_t)b * NPTS * 3;
    const int base = w * SEG;

    // register-resident point state
    float px[PPT], py[PPT], pz[PPT], pd[PPT];
    u32 inv[PPT];
    #pragma unroll
    for (int j = 0; j < PPT; ++j) {
        int idx = base + j * TPB + tid;          // coalesced initial load
        px[j] = xb[(size_t)idx * 3 + 0];
        py[j] = xb[(size_t)idx * 3 + 1];
        pz[j] = xb[(size_t)idx * 3 + 2];
        pd[j] = 1e10f;
        inv[j] = (u32)(NPTS - 1 - idx);
    }

    __shared__ u64   lds_keys[NWAVE];
    __shared__ float lds_cx[NWAVE], lds_cy[NWAVE], lds_cz[NWAVE];
    __shared__ float bc[3];

    const int f0 = finit[b];
    if (w == 0 && tid == 0) out[b * NPOINT] = f0;
    float cx = xb[(size_t)f0 * 3 + 0];
    float cy = xb[(size_t)f0 * 3 + 1];
    float cz = xb[(size_t)f0 * 3 + 2];

    u64* bp = ring + (size_t)b * 2 * 64;         // [2 parity][4 words][16 peers]

    for (int t = 1; t < NPOINT; ++t) {
        // ---- pass1: distance update (golden fp32 form) + 4-way max trees ----
        float m0 = -1.0f, m1 = -1.0f, m2 = -1.0f, m3 = -1.0f;
        #pragma unroll
        for (int j = 0; j < PPT; ++j) {
            float dx = __fsub_rn(px[j], cx);
            float dy = __fsub_rn(py[j], cy);
            float dz = __fsub_rn(pz[j], cz);
            float d  = __fmaf_rn(dz, dz, __fmaf_rn(dy, dy, __fmul_rn(dx, dx)));
            float nd = fminf(pd[j], d);
            pd[j] = nd;
            if ((j & 3) == 0)      m0 = fmaxf(m0, nd);
            else if ((j & 3) == 1) m1 = fmaxf(m1, nd);
            else if ((j & 3) == 2) m2 = fmaxf(m2, nd);
            else                   m3 = fmaxf(m3, nd);
        }
        float mx = fmaxf(fmaxf(m0, m1), fmaxf(m2, m3));
        u32 mxb = wave_umax(__float_as_uint(mx));          // wave max
        // ---- pass2: max inv among wave-level ties ----
        u32 b0 = 0, b1 = 0, b2 = 0, b3 = 0;
        #pragma unroll
        for (int j = 0; j < PPT; ++j) {
            bool tie = (__float_as_uint(pd[j]) == mxb);
            if ((j & 3) == 0)      b0 = tie ? umax_(b0, inv[j]) : b0;
            else if ((j & 3) == 1) b1 = tie ? umax_(b1, inv[j]) : b1;
            else if ((j & 3) == 2) b2 = tie ? umax_(b2, inv[j]) : b2;
            else                   b3 = tie ? umax_(b3, inv[j]) : b3;
        }
        u32 bv = wave_umax(umax_(umax_(b0, b1), umax_(b2, b3)));
        // ---- wave-winner coords from registers (pre-barrier, amortized) ----
        int local    = ((NPTS - 1) - (int)bv) - base;      // j*TPB + tid
        int jwin     = local >> 9;                         // TPB=512
        int lane_win = local & 63;
        float sx, sy, sz;
        SEL16(px, jwin, sx); SEL16(py, jwin, sy); SEL16(pz, jwin, sz);
        sx = __shfl(sx, lane_win, 64);
        sy = __shfl(sy, lane_win, 64);
        sz = __shfl(sz, lane_win, 64);
        if (lane == 0) {
            lds_keys[wv] = ((u64)mxb << 17) | (u64)bv;
            lds_cx[wv] = sx; lds_cy[wv] = sy; lds_cz[wv] = sz;
        }
        __syncthreads();

        const int p = t & 1;
        if (wv == 0) {
            const u64 tt = (u64)(u32)t;
            const u64 tg = tt << 49;
            // block reduce: 8 keys duplicated over row16, DPP all-reduce
            u64 kb = lds_keys[lane & (NWAVE - 1)];
            kb = row16_umax64(kb);                 // all lanes hold block max
            // block-winner wave + coords (uniform LDS broadcast reads)
            int blocal = ((NPTS - 1) - (int)(kb & 0x1FFFF)) - base;
            int Wst    = (blocal >> 6) & (NWAVE - 1);
            float wx = lds_cx[Wst], wy = lds_cy[Wst], wz = lds_cz[Wst];
            // publish 4 word-major words (lanes 0-3, parallel stores)
            u64* bpp = bp + (p << 6);              // [4 words][16 peers]
            u64 pval = (lane == 0) ? (tg | kb)
                     : (lane == 1) ? (tg | ((u64)__float_as_uint(wx) << 17))
                     : (lane == 2) ? (tg | ((u64)__float_as_uint(wy) << 17))
                     :               (tg | ((u64)__float_as_uint(wz) << 17));
            if (lane < 4)
                __hip_atomic_store(&bpp[(lane << 4) | w], pval,
                                   __ATOMIC_RELAXED, __HIP_MEMORY_SCOPE_AGENT);
            // poll: word=lane>>4, peer=lane&15; self substituted (R8 shape)
            const int peer = lane & 15, word = lane >> 4;
            u64 g = (word == 0) ? (tg | kb)
                  : (word == 1) ? (tg | ((u64)__float_as_uint(wx) << 17))
                  : (word == 2) ? (tg | ((u64)__float_as_uint(wy) << 17))
                  :               (tg | ((u64)__float_as_uint(wz) << 17));
            if (peer != w) {
                u64* sp = &bpp[(word << 4) | peer];
                u64 ga = __hip_atomic_load(sp, __ATOMIC_RELAXED, __HIP_MEMORY_SCOPE_AGENT);
                for (;;) {                         // 2-deep pipelined (R8)
                    u64 gb = __hip_atomic_load(sp, __ATOMIC_RELAXED, __HIP_MEMORY_SCOPE_AGENT);
                    if ((ga >> 49) == tt) { g = ga; break; }
                    ga = __hip_atomic_load(sp, __ATOMIC_RELAXED, __HIP_MEMORY_SCOPE_AGENT);
                    if ((gb >> 49) == tt) { g = gb; break; }
                }
            }
            // winner over 16 peers (key words live on lanes 0-15)
            u64 K  = row16_umax64((lane < 16) ? g : 0);
            u64 K0 = shfl_u64(K, 0);
            int bi    = (NPTS - 1) - (int)(K0 & 0x1FFFF);
            int Pstar = bi >> SEGSH;               // winner's owner WG
            u64 gx = shfl_u64(g, 16 + Pstar);
            u64 gy = shfl_u64(g, 32 + Pstar);
            u64 gz = shfl_u64(g, 48 + Pstar);
            if (lane == 0) {
                bc[0] = __uint_as_float((u32)(gx >> 17));
                bc[1] = __uint_as_float((u32)(gy >> 17));
                bc[2] = __uint_as_float((u32)(gz >> 17));
                if (w == 0) out[b * NPOINT + t] = bi;
            }
        }
        __syncthreads();
        cx = bc[0]; cy = bc[1]; cz = bc[2];
    }
}

extern "C" void kernel_launch(void* const* d_in, const int* in_sizes, int n_in,
                              void* d_out, int out_size, void* d_ws, size_t ws_size,
                              hipStream_t stream) {
    const float* xyz   = (const float*)d_in[0];
    const int*   finit = (const int*)d_in[1];
    int*         out   = (int*)d_out;
    u64*         ring  = (u64*)d_ws;   // 16*2*64*8 = 16 KiB; tag-checked, no init

    void* args[] = { (void*)&xyz, (void*)&finit, (void*)&out, (void*)&ring };
    dim3 grid(NBATCH * KWG), block(TPB);
    if (hipLaunchCooperativeKernel((const void*)fps_kernel, grid, block, args, 0, stream)
        != hipSuccess) {
        // 256 blocks x 8 waves, 1 WG/CU -> co-resident anyway
        fps_kernel<<<grid, block, 0, stream>>>(xyz, finit, out, ring);
    }
}

// Round 13
// 8300.497 us; speedup vs baseline: 1.2575x; 1.1534x over previous
//
#include <hip/hip_runtime.h>
#include <stdint.h>

#define NBATCH 16
#define NPTS   131072
#define NPOINT 4096
#define KWG    16                    // workgroups per batch
#define TPB    512
#define NWAVE  (TPB/64)              // 8
#define PPT    (NPTS/(KWG*TPB))      // 16 points per thread
#define SEG    (NPTS/KWG)            // 8192
#define SEGSH  13                    // log2(SEG)

typedef unsigned long long u64;
typedef unsigned int u32;

// ---- DPP helpers (R8-proven) ----
template<int CTRL>
__device__ __forceinline__ u32 dpp32(u32 x) {
    return (u32)__builtin_amdgcn_update_dpp(0, (int)x, CTRL, 0xf, 0xf, true);
}
__device__ __forceinline__ u32 umax_(u32 a, u32 b) { return a > b ? a : b; }

__device__ __forceinline__ u32 wave_umax(u32 x) {
    x = umax_(x, dpp32<0xB1>(x));    // quad_perm xor1
    x = umax_(x, dpp32<0x4E>(x));    // quad_perm xor2
    x = umax_(x, dpp32<0x124>(x));   // row_ror:4
    x = umax_(x, dpp32<0x128>(x));   // row_ror:8 -> row16 all-reduced
    x = umax_(x, (u32)__builtin_amdgcn_ds_swizzle((int)x, 0x401F)); // xor16
    x = umax_(x, (u32)__shfl_xor((int)x, 32, 64));                  // xor32
    return x;
}
template<int CTRL>
__device__ __forceinline__ u64 dpp64max(u64 x) {
    u32 lo = dpp32<CTRL>((u32)x);
    u32 hi = dpp32<CTRL>((u32)(x >> 32));
    u64 o = ((u64)hi << 32) | lo;
    return o > x ? o : x;
}
__device__ __forceinline__ u64 row16_umax64(u64 k) {
    k = dpp64max<0xB1>(k);
    k = dpp64max<0x4E>(k);
    k = dpp64max<0x124>(k);
    k = dpp64max<0x128>(k);
    return k;
}

// slot word: [tag:15][dist_f32_bits:32][inv:17]; ring [batch][parity][16 peers]
// (2-line key region; R9/R11/R12 proved any wider publish/poll set loses.)
// Depth-2 parity ring safety (all-wave-consumer form): WG A publishes t+2
// only after A computed round t+2, which required ALL of A's waves to read
// keys(t+1), which required every peer's publish(t+1), which required each
// peer's waves to have read keys(t) -> nobody can still need slot[p] from
// round t when it is overwritten at t+2. Poison tag (0xAA.. -> 21845) never
// matches a round tag; replay-stale values are deterministic-identical.
__global__ __launch_bounds__(TPB, 2) void fps_kernel(
    const float* __restrict__ xyz, const int* __restrict__ finit,
    int* __restrict__ out, u64* __restrict__ ring)
{
    const int b    = blockIdx.x >> 4;
    const int w    = blockIdx.x & 15;
    const int tid  = threadIdx.x;
    const int lane = tid & 63;
    const int wv   = tid >> 6;

    const float* xb = xyz + (size_t)b * NPTS * 3;
    const int base = w * SEG;

    // register-resident point state
    float px[PPT], py[PPT], pz[PPT], pd[PPT];
    u32 inv[PPT];
    #pragma unroll
    for (int j = 0; j < PPT; ++j) {
        int idx = base + j * TPB + tid;          // coalesced initial load
        px[j] = xb[(size_t)idx * 3 + 0];
        py[j] = xb[(size_t)idx * 3 + 1];
        pz[j] = xb[(size_t)idx * 3 + 2];
        pd[j] = 1e10f;
        inv[j] = (u32)(NPTS - 1 - idx);
    }

    __shared__ u64 lds_keys[NWAVE];

    const int f0 = finit[b];
    if (w == 0 && tid == 0) out[b * NPOINT] = f0;
    float cx = xb[(size_t)f0 * 3 + 0];
    float cy = xb[(size_t)f0 * 3 + 1];
    float cz = xb[(size_t)f0 * 3 + 2];

    u64* bp = ring + (size_t)b * 2 * KWG;        // [2 parity][16 peers]

    for (int t = 1; t < NPOINT; ++t) {
        // ---- pass1: distance update (golden fp32 form) + 4-way max trees ----
        float m0 = -1.0f, m1 = -1.0f, m2 = -1.0f, m3 = -1.0f;
        #pragma unroll
        for (int j = 0; j < PPT; ++j) {
            float dx = __fsub_rn(px[j], cx);
            float dy = __fsub_rn(py[j], cy);
            float dz = __fsub_rn(pz[j], cz);
            float d  = __fmaf_rn(dz, dz, __fmaf_rn(dy, dy, __fmul_rn(dx, dx)));
            float nd = fminf(pd[j], d);
            pd[j] = nd;
            if ((j & 3) == 0)      m0 = fmaxf(m0, nd);
            else if ((j & 3) == 1) m1 = fmaxf(m1, nd);
            else if ((j & 3) == 2) m2 = fmaxf(m2, nd);
            else                   m3 = fmaxf(m3, nd);
        }
        float mx = fmaxf(fmaxf(m0, m1), fmaxf(m2, m3));
        u32 mxb = wave_umax(__float_as_uint(mx));          // wave max
        // ---- pass2: max inv among wave-level ties ----
        u32 b0 = 0, b1 = 0, b2 = 0, b3 = 0;
        #pragma unroll
        for (int j = 0; j < PPT; ++j) {
            bool tie = (__float_as_uint(pd[j]) == mxb);
            if ((j & 3) == 0)      b0 = tie ? umax_(b0, inv[j]) : b0;
            else if ((j & 3) == 1) b1 = tie ? umax_(b1, inv[j]) : b1;
            else if ((j & 3) == 2) b2 = tie ? umax_(b2, inv[j]) : b2;
            else                   b3 = tie ? umax_(b3, inv[j]) : b3;
        }
        u32 bv = wave_umax(umax_(umax_(b0, b1), umax_(b2, b3)));
        if (lane == 0)
            lds_keys[wv] = ((u64)mxb << 17) | (u64)bv;
        __syncthreads();                                   // the ONE barrier

        const int p  = t & 1;
        const u64 tt = (u64)(u32)t;
        const u64 tg = tt << 49;
        // ---- every wave: block reduce over the 8 wave-keys (DPP row16) ----
        u64 kb = lds_keys[lane & (NWAVE - 1)];
        kb = row16_umax64(kb);                  // all lanes hold block max
        u64* bpp = bp + (p << 4);
        // publish: wave0 lane0 only (single word -> 2-line poll set total)
        if (wv == 0 && lane == 0)
            __hip_atomic_store(&bpp[w], tg | kb, __ATOMIC_RELAXED,
                               __HIP_MEMORY_SCOPE_AGENT);
        // ---- every wave polls (lane<16: peer=lane, self substituted) ----
        u64 g = tg | kb;
        if (lane < 16 && lane != w) {
            u64* sp = &bpp[lane];
            u64 ga = __hip_atomic_load(sp, __ATOMIC_RELAXED, __HIP_MEMORY_SCOPE_AGENT);
            for (;;) {                          // 2-deep pipelined (R8-proven)
                u64 gb = __hip_atomic_load(sp, __ATOMIC_RELAXED, __HIP_MEMORY_SCOPE_AGENT);
                if ((ga >> 49) == tt) { g = ga; break; }
                ga = __hip_atomic_load(sp, __ATOMIC_RELAXED, __HIP_MEMORY_SCOPE_AGENT);
                if ((gb >> 49) == tt) { g = gb; break; }
            }
        }
        // speculative per-peer coord fetch (parallel, L2/LLC-served)
        float sxl = 0.f, syl = 0.f, szl = 0.f;
        if (lane < 16) {
            int bi_l = (NPTS - 1) - (int)(g & 0x1FFFF);
            const float* cp = &xb[(size_t)bi_l * 3];
            sxl = cp[0]; syl = cp[1]; szl = cp[2];
        }
        // winner over 16 peers: row16 DPP all-reduce (lanes 0-15 = row 0)
        u64 K = row16_umax64((lane < 16) ? g : 0);
        // broadcast key from lane 0 to the whole wave
        u32 Klo = (u32)__shfl((int)(u32)K, 0, 64);
        u32 Khi = (u32)__shfl((int)(u32)(K >> 32), 0, 64);
        u64 K0  = ((u64)Khi << 32) | Klo;
        int bi    = (NPTS - 1) - (int)(K0 & 0x1FFFF);
        int Pstar = bi >> SEGSH;                // winner's owner WG
        cx = __shfl(sxl, Pstar, 64);
        cy = __shfl(syl, Pstar, 64);
        cz = __shfl(szl, Pstar, 64);
        if (wv == 0 && lane == 0 && w == 0) out[b * NPOINT + t] = bi;
        // no second barrier: each wave computed cx/cy/cz itself
    }
}

extern "C" void kernel_launch(void* const* d_in, const int* in_sizes, int n_in,
                              void* d_out, int out_size, void* d_ws, size_t ws_size,
                              hipStream_t stream) {
    const float* xyz   = (const float*)d_in[0];
    const int*   finit = (const int*)d_in[1];
    int*         out   = (int*)d_out;
    u64*         ring  = (u64*)d_ws;   // 16*2*16*8 = 4 KiB; tag-checked, no init

    void* args[] = { (void*)&xyz, (void*)&finit, (void*)&out, (void*)&ring };
    dim3 grid(NBATCH * KWG), block(TPB);
    if (hipLaunchCooperativeKernel((const void*)fps_kernel, grid, block, args, 0, stream)
        != hipSuccess) {
        // 256 blocks x 8 waves, 1 WG/CU -> co-resident anyway
        fps_kernel<<<grid, block, 0, stream>>>(xyz, finit, out, ring);
    }
}

// Round 14
// 7958.266 us; speedup vs baseline: 1.3116x; 1.0430x over previous
//
#include <hip/hip_runtime.h>
#include <stdint.h>

#define NBATCH 16
#define NPTS   131072
#define NPOINT 4096
#define KWG    16                    // workgroups per batch
#define TPB    1024
#define NWAVE  (TPB/64)              // 16
#define PPT    (NPTS/(KWG*TPB))      // 8 points per thread
#define SEG    (NPTS/KWG)            // 8192
#define SEGSH  13                    // log2(SEG)

typedef unsigned long long u64;
typedef unsigned int u32;

// ---- DPP helpers (R8-proven) ----
template<int CTRL>
__device__ __forceinline__ u32 dpp32(u32 x) {
    return (u32)__builtin_amdgcn_update_dpp(0, (int)x, CTRL, 0xf, 0xf, true);
}
__device__ __forceinline__ u32 umax_(u32 a, u32 b) { return a > b ? a : b; }

__device__ __forceinline__ u32 wave_umax(u32 x) {
    x = umax_(x, dpp32<0xB1>(x));    // quad_perm xor1
    x = umax_(x, dpp32<0x4E>(x));    // quad_perm xor2
    x = umax_(x, dpp32<0x124>(x));   // row_ror:4
    x = umax_(x, dpp32<0x128>(x));   // row_ror:8 -> row16 all-reduced
    x = umax_(x, (u32)__builtin_amdgcn_ds_swizzle((int)x, 0x401F)); // xor16
    x = umax_(x, (u32)__shfl_xor((int)x, 32, 64));                  // xor32
    return x;
}
template<int CTRL>
__device__ __forceinline__ u64 dpp64max(u64 x) {
    u32 lo = dpp32<CTRL>((u32)x);
    u32 hi = dpp32<CTRL>((u32)(x >> 32));
    u64 o = ((u64)hi << 32) | lo;
    return o > x ? o : x;
}
__device__ __forceinline__ u64 row16_umax64(u64 k) {
    k = dpp64max<0xB1>(k);
    k = dpp64max<0x4E>(k);
    k = dpp64max<0x124>(k);
    k = dpp64max<0x128>(k);
    return k;
}
__device__ __forceinline__ u64 shfl_u64(u64 v, int s) {
    u32 lo = (u32)__shfl((int)(u32)v, s, 64);
    u32 hi = (u32)__shfl((int)(u32)(v >> 32), s, 64);
    return ((u64)hi << 32) | lo;
}

// slot word: [tag:15][dist_f32_bits:32][inv:17]; ring [batch][parity][16 peers]
// (2-line key region, single-word publish, wave0-only poll — R8-optimal; all
// wider layouts (R9/R11/R12) and all-wave consumers (R13) measured worse.)
// Depth-2 parity ring safety: producer reuses slot[p] at t+2 only after its
// barrier(t+1), which requires its wave0 consumed all round-t+1 keys, which
// requires every peer published t+1, which requires each peer's barrier(t)
// and hence consumption of round t. Poison tag (0xAA.. -> 21845) never
// matches a round tag (<4096); replay-stale values are deterministic-
// identical to fresh ones -> benign (validated across R4-R13 replay sets).
__global__ __launch_bounds__(TPB, 4) void fps_kernel(
    const float* __restrict__ xyz, const int* __restrict__ finit,
    int* __restrict__ out, u64* __restrict__ ring)
{
    const int b    = blockIdx.x >> 4;
    const int w    = blockIdx.x & 15;
    const int tid  = threadIdx.x;
    const int lane = tid & 63;
    const int wv   = tid >> 6;

    const float* xb = xyz + (size_t)b * NPTS * 3;
    const int base = w * SEG;

    // register-resident point state
    float px[PPT], py[PPT], pz[PPT], pd[PPT];
    u32 inv[PPT];
    #pragma unroll
    for (int j = 0; j < PPT; ++j) {
        int idx = base + j * TPB + tid;          // coalesced initial load
        px[j] = xb[(size_t)idx * 3 + 0];
        py[j] = xb[(size_t)idx * 3 + 1];
        pz[j] = xb[(size_t)idx * 3 + 2];
        pd[j] = 1e10f;
        inv[j] = (u32)(NPTS - 1 - idx);
    }

    __shared__ u64   lds_keys[NWAVE];
    __shared__ float bc[3];

    const int f0 = finit[b];
    if (w == 0 && tid == 0) out[b * NPOINT] = f0;
    float cx = xb[(size_t)f0 * 3 + 0];
    float cy = xb[(size_t)f0 * 3 + 1];
    float cz = xb[(size_t)f0 * 3 + 2];

    u64* bp = ring + (size_t)b * 2 * KWG;        // [2 parity][16 peers]

    for (int t = 1; t < NPOINT; ++t) {
        // ---- pass1: distance update (golden fp32 form) + 2-way max trees ----
        float m0 = -1.0f, m1 = -1.0f;
        #pragma unroll
        for (int j = 0; j < PPT; ++j) {
            float dx = __fsub_rn(px[j], cx);
            float dy = __fsub_rn(py[j], cy);
            float dz = __fsub_rn(pz[j], cz);
            float d  = __fmaf_rn(dz, dz, __fmaf_rn(dy, dy, __fmul_rn(dx, dx)));
            float nd = fminf(pd[j], d);
            pd[j] = nd;
            if ((j & 1) == 0) m0 = fmaxf(m0, nd);
            else              m1 = fmaxf(m1, nd);
        }
        float mx = fmaxf(m0, m1);
        u32 mxb = wave_umax(__float_as_uint(mx));          // wave max
        // ---- pass2: max inv among wave-level ties ----
        u32 b0 = 0, b1 = 0;
        #pragma unroll
        for (int j = 0; j < PPT; ++j) {
            bool tie = (__float_as_uint(pd[j]) == mxb);
            if ((j & 1) == 0) b0 = tie ? umax_(b0, inv[j]) : b0;
            else              b1 = tie ? umax_(b1, inv[j]) : b1;
        }
        u32 bv = wave_umax(umax_(b0, b1));
        if (lane == 0)
            lds_keys[wv] = ((u64)mxb << 17) | (u64)bv;
        __syncthreads();

        const int p = t & 1;
        if (wv == 0) {
            const u64 tt = (u64)(u32)t;
            const u64 tg = tt << 49;
            // block reduce: 16 wave-keys exactly fill row16, DPP all-reduce
            u64 kb = lds_keys[lane & (NWAVE - 1)];
            kb = row16_umax64(kb);                  // lanes 0-15 hold block max
            u64* bpp = bp + (p << 4);
            if (lane == 0)
                __hip_atomic_store(&bpp[w], tg | kb, __ATOMIC_RELAXED,
                                   __HIP_MEMORY_SCOPE_AGENT);
            // poll peer(lane); self substituted; 2-deep pipelined (R8-proven)
            u64 g = tg | kb;
            if (lane < 16 && lane != w) {
                u64* sp = &bpp[lane];
                u64 ga = __hip_atomic_load(sp, __ATOMIC_RELAXED, __HIP_MEMORY_SCOPE_AGENT);
                for (;;) {
                    u64 gb = __hip_atomic_load(sp, __ATOMIC_RELAXED, __HIP_MEMORY_SCOPE_AGENT);
                    if ((ga >> 49) == tt) { g = ga; break; }
                    ga = __hip_atomic_load(sp, __ATOMIC_RELAXED, __HIP_MEMORY_SCOPE_AGENT);
                    if ((gb >> 49) == tt) { g = gb; break; }
                }
            }
            // speculative coord prefetch (overlaps remaining peers' polls)
            float sxl = 0.f, syl = 0.f, szl = 0.f;
            if (lane < 16) {
                int bi_l = (NPTS - 1) - (int)(g & 0x1FFFF);
                sxl = xb[(size_t)bi_l * 3 + 0];
                syl = xb[(size_t)bi_l * 3 + 1];
                szl = xb[(size_t)bi_l * 3 + 2];
            }
            // winner over 16 peers: row16 DPP all-reduce (lanes 0-15 = row 0)
            u64 K = row16_umax64((lane < 16) ? g : 0);
            if (lane < 16) {
                int bi    = (NPTS - 1) - (int)(K & 0x1FFFF);
                int Pstar = bi >> SEGSH;            // winner's owner WG
                float cxn = __shfl(sxl, Pstar, 64);
                float cyn = __shfl(syl, Pstar, 64);
                float czn = __shfl(szl, Pstar, 64);
                if (lane == 0) {
                    bc[0] = cxn; bc[1] = cyn; bc[2] = czn;
                    if (w == 0) out[b * NPOINT + t] = bi;
                }
            }
        }
        __syncthreads();
        cx = bc[0]; cy = bc[1]; cz = bc[2];
    }
}

extern "C" void kernel_launch(void* const* d_in, const int* in_sizes, int n_in,
                              void* d_out, int out_size, void* d_ws, size_t ws_size,
                              hipStream_t stream) {
    const float* xyz   = (const float*)d_in[0];
    const int*   finit = (const int*)d_in[1];
    int*         out   = (int*)d_out;
    u64*         ring  = (u64*)d_ws;   // 16*2*16*8 = 4 KiB; tag-checked, no init

    void* args[] = { (void*)&xyz, (void*)&finit, (void*)&out, (void*)&ring };
    dim3 grid(NBATCH * KWG), block(TPB);
    if (hipLaunchCooperativeKernel((const void*)fps_kernel, grid, block, args, 0, stream)
        != hipSuccess) {
        // 256 blocks x 16 waves, 1 WG/CU -> co-resident anyway
        fps_kernel<<<grid, block, 0, stream>>>(xyz, finit, out, ring);
    }
}